// Round 2
// baseline (300.867 us; speedup 1.0000x reference)
//
#include <hip/hip_runtime.h>
#include <hip/hip_bf16.h>

#define H_ 96
#define W_ 96
#define HW_ 9216
#define C_ 256
#define B_ 2
#define KO_ 27
#define EPS_ 1e-5f
#define NCH_ 72   // 9 k-taps * 8 c-chunks of 32

typedef unsigned short ushort8 __attribute__((ext_vector_type(8)));
typedef short short8v __attribute__((ext_vector_type(8)));
typedef float float4v __attribute__((ext_vector_type(4)));

__device__ __forceinline__ float b2f(unsigned short u) {
    return __uint_as_float(((unsigned int)u) << 16);
}
__device__ __forceinline__ unsigned short f2b(float f) {
    __hip_bfloat16 h = __float2bfloat16(f);
    union { __hip_bfloat16 h; unsigned short u; } cv; cv.h = h; return cv.u;
}
__device__ __forceinline__ unsigned int pack2(float a, float b) {
    union { __hip_bfloat162 h; unsigned int u; } cv;
    cv.h = __float22bfloat162_rn(make_float2(a, b));
    return cv.u;
}

// ---------------- kernel 1: weight repack (fragment-ordered) + BN fold -------
// WQ[((k*8 + c/32)*256 + o)*32 + (c%32)] = bf16(w_conv[o][c][k])
__global__ __launch_bounds__(256) void prep_w_kernel(
    const float* __restrict__ w_conv, const float* __restrict__ b_conv,
    const float* __restrict__ gamma, const float* __restrict__ beta,
    const float* __restrict__ rmean, const float* __restrict__ rvar,
    float* __restrict__ AB, unsigned short* __restrict__ WQ)
{
    int idx = blockIdx.x * 256 + threadIdx.x;   // 589824 total
    if (blockIdx.x == 0) {
        int o = threadIdx.x;
        float sc = gamma[o] * rsqrtf(rvar[o] + EPS_);
        AB[o] = sc;
        AB[256 + o] = beta[o] + (b_conv[o] - rmean[o]) * sc;
    }
    int ch = idx >> 13;          // chunk = k*8 + c/32
    int o  = (idx >> 5) & 255;
    int cp = idx & 31;
    int c  = ((ch & 7) << 5) + cp;
    int k  = ch >> 3;
    WQ[idx] = f2b(w_conv[(o * C_ + c) * 9 + k]);
}

// ---------------- kernel 2: x NCHW f32 -> NHWC bf16 ----------------
__global__ __launch_bounds__(256) void xt_kernel(const float* __restrict__ x,
                                                 unsigned short* __restrict__ XT)
{
    __shared__ unsigned short ls[32][100];
    int h  = blockIdx.x;
    int cg = blockIdx.y & 7;
    int b  = blockIdx.y >> 3;
    int c0 = cg * 32;
    for (int e = threadIdx.x; e < 32 * W_; e += 256) {
        int ci = e / W_, w = e % W_;
        ls[ci][w] = f2b(x[((b * C_ + c0 + ci) * H_ + h) * W_ + w]);
    }
    __syncthreads();
    for (int e = threadIdx.x; e < 32 * W_; e += 256) {
        int w = e >> 5, ci = e & 31;
        XT[((b * H_ + h) * W_ + w) * C_ + c0 + ci] = ls[ci][w];
    }
}

// ---------------- kernel 3: offset conv (fp32), c-split 8 ----------------
__global__ __launch_bounds__(256) void offconv_kernel(const float* __restrict__ x,
    const float* __restrict__ w_off, float* __restrict__ PART)
{
    __shared__ float xs[8][18][18];
    const int tile = blockIdx.x, b = blockIdx.y, s = blockIdx.z;
    const int h0 = (tile / 6) * 16, w0 = (tile % 6) * 16;
    const int tid = threadIdx.x;
    const int py = tid >> 4, px = tid & 15;
    float acc[27];
#pragma unroll
    for (int i = 0; i < 27; i++) acc[i] = 0.f;

    for (int g = 0; g < 4; ++g) {          // 4 groups of 8 channels
        const int cb = s * 32 + g * 8;
        __syncthreads();
        for (int e = tid; e < 8 * 324; e += 256) {
            int ci = e / 324, r2 = e - ci * 324;
            int r = r2 / 18, cl = r2 - r * 18;
            int gy = h0 + r - 1, gx = w0 + cl - 1;
            float v = 0.f;
            if ((unsigned)gy < (unsigned)H_ && (unsigned)gx < (unsigned)W_)
                v = x[((b * C_ + cb + ci) * H_ + gy) * W_ + gx];
            xs[ci][r][cl] = v;
        }
        __syncthreads();
#pragma unroll 1
        for (int ci = 0; ci < 8; ++ci) {
            float xv[9];
#pragma unroll
            for (int a = 0; a < 3; a++)
#pragma unroll
                for (int q = 0; q < 3; q++)
                    xv[a * 3 + q] = xs[ci][py + a][px + q];
            const float* wb = w_off + (cb + ci) * 9;
#pragma unroll
            for (int ko = 0; ko < 27; ++ko) {
                float a0 = acc[ko];
#pragma unroll
                for (int t = 0; t < 9; t++)
                    a0 = fmaf(xv[t], wb[ko * 2304 + t], a0);
                acc[ko] = a0;
            }
        }
    }
    int pix = (h0 + py) * W_ + (w0 + px);
    int base = ((s * B_ + b) * KO_) * HW_ + pix;
#pragma unroll
    for (int ko = 0; ko < 27; ko++)
        PART[base + ko * HW_] = acc[ko];
}

// ---------------- kernel 4: reduce partials -> DY/DX/MASK ----------------
__global__ __launch_bounds__(256) void finalize_kernel(const float* __restrict__ PART,
    const float* __restrict__ b_off, float* __restrict__ DY, float* __restrict__ DX,
    float* __restrict__ MK)
{
    int idx = blockIdx.x * 256 + threadIdx.x;   // < 2*27*9216
    int b = idx / (KO_ * HW_);
    int r = idx % (KO_ * HW_);
    int ko = r / HW_;
    int pix = r % HW_;
    float v = b_off[ko];
#pragma unroll
    for (int s = 0; s < 8; s++)
        v += PART[((s * B_ + b) * KO_ + ko) * HW_ + pix];
    if (ko < 18) {
        int k = ko >> 1;
        float* dst = (ko & 1) ? DX : DY;
        dst[(b * 9 + k) * HW_ + pix] = v;
    } else {
        int k = ko - 18;
        MK[(b * 9 + k) * HW_ + pix] = 1.f / (1.f + expf(-v));
    }
}

// ---------------- kernel 5: deformable GEMM (bf16 MFMA), depth-2 pipeline ----
__global__ __launch_bounds__(256, 2) void deform_kernel(
    const float* __restrict__ x, const unsigned short* __restrict__ XT,
    const unsigned short* __restrict__ WQ,
    const float* __restrict__ DY, const float* __restrict__ DX,
    const float* __restrict__ MK, const float* __restrict__ AB,
    float* __restrict__ out)
{
    // 144B row stride: 8 consecutive rows cover all 32 banks -> conflict-free
    __shared__ __align__(16) unsigned short s_s[2][64][72];

    const int tid = threadIdx.x;
    const int b  = blockIdx.z;
    const int o0 = blockIdx.y * 128;
    const int ht = blockIdx.x / 6, wt = blockIdx.x % 6;
    const int h0 = ht * 4, w0 = wt * 16;

    // s-fill mapping: 4 lanes per pixel (8-channel subgroups)
    const int sub  = tid & 3;
    const int pp_f = tid >> 2;
    const int ph_f = h0 + (pp_f >> 4);
    const int pw_f = w0 + (pp_f & 15);
    const int pix_f = ph_f * W_ + pw_f;

    // gemm mapping
    const int wave = tid >> 6;
    const int lane = tid & 63;
    const int quad = lane >> 4;
    const int l15  = lane & 15;
    const int wo = (wave >> 1) * 64;
    const int wp = (wave & 1) * 32;

    const unsigned short* wbase = WQ + (o0 + wo + l15) * 32 + quad * 8;

    float4v acc[4][2];
#pragma unroll
    for (int i = 0; i < 4; i++)
#pragma unroll
        for (int j = 0; j < 2; j++)
            acc[i][j] = float4v{0.f, 0.f, 0.f, 0.f};

    const float* DYb = DY + b * 9 * HW_ + pix_f;
    const float* DXb = DX + b * 9 * HW_ + pix_f;
    const float* MKb = MK + b * 9 * HW_ + pix_f;

    int a00, a01, a10, a11;                 // gather offsets (shorts), incl sub*8
    float fwc0, fwc1, fwc2, fwc3;           // lerp weights for chunk being stored
    float fwn0, fwn1, fwn2, fwn3;           // next k-tap's weights
    float nk_dy = 0.f, nk_dx = 0.f, nk_m = 0.f;

    auto make_params = [&](int k, float dyv, float dxv, float m) {
        float py = (float)(ph_f + (k / 3) - 1) + dyv;
        float pxx = (float)(pw_f + (k % 3) - 1) + dxv;
        float y0f = floorf(py), x0f = floorf(pxx);
        float ly = py - y0f, lx = pxx - x0f;
        int y0 = (int)y0f, x0i = (int)x0f;
        int y1 = y0 + 1, x1 = x0i + 1;
        bool vy0 = (unsigned)y0 < (unsigned)H_;
        bool vy1 = (unsigned)y1 < (unsigned)H_;
        bool vx0 = (unsigned)x0i < (unsigned)W_;
        bool vx1 = (unsigned)x1 < (unsigned)W_;
        fwn0 = (vy0 && vx0) ? (1.f - ly) * (1.f - lx) * m : 0.f;
        fwn1 = (vy0 && vx1) ? (1.f - ly) * lx * m : 0.f;
        fwn2 = (vy1 && vx0) ? ly * (1.f - lx) * m : 0.f;
        fwn3 = (vy1 && vx1) ? ly * lx * m : 0.f;
        int y0c = min(max(y0, 0), H_ - 1), y1c = min(max(y1, 0), H_ - 1);
        int x0c = min(max(x0i, 0), W_ - 1), x1c = min(max(x1, 0), W_ - 1);
        a00 = ((b * H_ + y0c) * W_ + x0c) * C_ + sub * 8;
        a01 = ((b * H_ + y0c) * W_ + x1c) * C_ + sub * 8;
        a10 = ((b * H_ + y1c) * W_ + x0c) * C_ + sub * 8;
        a11 = ((b * H_ + y1c) * W_ + x1c) * C_ + sub * 8;
    };

    struct GS { ushort8 v00, v01, v10, v11; };
    short8v a_cur[4], a_nxt[4];
    GS g0, g1;

    auto load_g = [&](int ch, GS& g) {
        const int co = (ch & 7) * 32;
        g.v00 = *(const ushort8*)(XT + a00 + co);
        g.v01 = *(const ushort8*)(XT + a01 + co);
        g.v10 = *(const ushort8*)(XT + a10 + co);
        g.v11 = *(const ushort8*)(XT + a11 + co);
    };
    auto load_w = [&](int ch, short8v A[4]) {
        const unsigned short* p = wbase + ch * 8192;
#pragma unroll
        for (int mt = 0; mt < 4; ++mt)
            A[mt] = *(const short8v*)(p + mt * 512);
    };
    auto lerp_store = [&](const GS& g, unsigned short (*sw)[72]) {
        float v[8];
#pragma unroll
        for (int j = 0; j < 8; j++)
            v[j] = fwc0 * b2f(g.v00[j]) + fwc1 * b2f(g.v01[j])
                 + fwc2 * b2f(g.v10[j]) + fwc3 * b2f(g.v11[j]);
        uint4 sv;
        sv.x = pack2(v[0], v[1]);
        sv.y = pack2(v[2], v[3]);
        sv.z = pack2(v[4], v[5]);
        sv.w = pack2(v[6], v[7]);
        *(uint4*)&sw[pp_f][sub * 8] = sv;
    };

    // ---- prologue ----
    {
        float d0 = DYb[0], e0 = DXb[0], m0 = MKb[0];
        nk_dy = DYb[HW_]; nk_dx = DXb[HW_]; nk_m = MKb[HW_];   // k=1 prefetch
        make_params(0, d0, e0, m0);
        fwc0 = fwn0; fwc1 = fwn1; fwc2 = fwn2; fwc3 = fwn3;
    }
    load_g(0, g0);
    load_g(1, g1);
    load_w(0, a_cur);
    lerp_store(g0, s_s[0]);
    __syncthreads();

    auto step = [&](int ch, unsigned short (*sr)[72], unsigned short (*sw)[72],
                    GS& gld, GS& gst) {
        const int c2 = ch + 2;
        if (c2 < NCH_ && (c2 & 7) == 0) {
            const int k2 = c2 >> 3;
            make_params(k2, nk_dy, nk_dx, nk_m);
            if (k2 < 8) {
                nk_dy = DYb[(k2 + 1) * HW_];
                nk_dx = DXb[(k2 + 1) * HW_];
                nk_m  = MKb[(k2 + 1) * HW_];
            }
        }
        if (c2 < NCH_) load_g(c2, gld);          // lands 2 iterations later
        if (ch + 1 < NCH_) load_w(ch + 1, a_nxt); // lands 1 iteration later
        short8v b0 = *(const short8v*)&sr[wp + l15][quad * 8];
        short8v b1 = *(const short8v*)&sr[wp + 16 + l15][quad * 8];
#pragma unroll
        for (int mt = 0; mt < 4; ++mt) {
            acc[mt][0] = __builtin_amdgcn_mfma_f32_16x16x32_bf16(
                a_cur[mt], b0, acc[mt][0], 0, 0, 0);
            acc[mt][1] = __builtin_amdgcn_mfma_f32_16x16x32_bf16(
                a_cur[mt], b1, acc[mt][1], 0, 0, 0);
        }
        if (ch + 1 < NCH_) lerp_store(gst, sw);
        fwc0 = fwn0; fwc1 = fwn1; fwc2 = fwn2; fwc3 = fwn3;
#pragma unroll
        for (int mt = 0; mt < 4; ++mt) a_cur[mt] = a_nxt[mt];
        if (ch + 1 < NCH_) __syncthreads();
    };

    for (int it = 0; it < NCH_; it += 2) {
        step(it,     s_s[0], s_s[1], g0, g1);
        step(it + 1, s_s[1], s_s[0], g1, g0);
    }

    // ---- epilogue: BN fold + relu + residual ----
    const float* Ao = AB;
    const float* Bo = AB + 256;
#pragma unroll
    for (int mt = 0; mt < 4; mt++) {
#pragma unroll
        for (int nt = 0; nt < 2; nt++) {
            int p = wp + nt * 16 + l15;
            int ph = h0 + (p >> 4), pw = w0 + (p & 15);
#pragma unroll
            for (int r = 0; r < 4; r++) {
                int o = o0 + wo + mt * 16 + quad * 4 + r;
                float v = acc[mt][nt][r] * Ao[o] + Bo[o];
                v = fmaxf(v, 0.f);
                int gi = ((b * C_ + o) * H_ + ph) * W_ + pw;
                out[gi] = x[gi] + v;
            }
        }
    }
}

extern "C" void kernel_launch(void* const* d_in, const int* in_sizes, int n_in,
                              void* d_out, int out_size, void* d_ws, size_t ws_size,
                              hipStream_t stream)
{
    (void)in_sizes; (void)n_in; (void)out_size; (void)ws_size;
    const float* x      = (const float*)d_in[0];
    const float* w_off  = (const float*)d_in[1];
    const float* b_off  = (const float*)d_in[2];
    const float* w_conv = (const float*)d_in[3];
    const float* b_conv = (const float*)d_in[4];
    const float* gamma  = (const float*)d_in[5];
    const float* beta   = (const float*)d_in[6];
    const float* rmean  = (const float*)d_in[7];
    const float* rvar   = (const float*)d_in[8];
    float* out = (float*)d_out;

    float* ws = (float*)d_ws;
    float* DY   = ws;                          // 2*9*9216
    float* DX   = DY + 2 * 9 * HW_;
    float* MK   = DX + 2 * 9 * HW_;
    float* PART = MK + 2 * 9 * HW_;            // 8*2*27*9216
    float* AB   = PART + 8 * 2 * 27 * HW_;     // 512
    unsigned short* WQ = (unsigned short*)(AB + 512);   // 589824 bf16
    unsigned short* XT = WQ + 589824;                   // 2*96*96*256 bf16

    prep_w_kernel<<<2304, 256, 0, stream>>>(w_conv, b_conv, gamma, beta, rmean, rvar, AB, WQ);
    xt_kernel<<<dim3(96, 16), 256, 0, stream>>>(x, XT);
    offconv_kernel<<<dim3(36, 2, 8), 256, 0, stream>>>(x, w_off, PART);
    finalize_kernel<<<1944, 256, 0, stream>>>(PART, b_off, DY, DX, MK);
    deform_kernel<<<dim3(144, 2, 2), 256, 0, stream>>>(x, XT, WQ, DY, DX, MK, AB, out);
}

// Round 3
// 209.387 us; speedup vs baseline: 1.4369x; 1.4369x over previous
//
#include <hip/hip_runtime.h>
#include <hip/hip_bf16.h>

#define H_ 96
#define W_ 96
#define HW_ 9216
#define C_ 256
#define B_ 2
#define KO_ 27
#define EPS_ 1e-5f
#define NCH_ 72   // 9 k-taps * 8 c-chunks of 32

typedef unsigned short ushort8 __attribute__((ext_vector_type(8)));
typedef short short8v __attribute__((ext_vector_type(8)));
typedef float float4v __attribute__((ext_vector_type(4)));

__device__ __forceinline__ float b2f(unsigned short u) {
    return __uint_as_float(((unsigned int)u) << 16);
}
__device__ __forceinline__ unsigned short f2b(float f) {
    __hip_bfloat16 h = __float2bfloat16(f);
    union { __hip_bfloat16 h; unsigned short u; } cv; cv.h = h; return cv.u;
}
__device__ __forceinline__ unsigned int pack2(float a, float b) {
    union { __hip_bfloat162 h; unsigned int u; } cv;
    cv.h = __float22bfloat162_rn(make_float2(a, b));
    return cv.u;
}

// ---------------- kernel 1: weight repacks + BN fold -------
// blocks [0,2304):   WQ[((k*8+c/32)*256+o)*32 + c%32] = bf16(w_conv[o][c][k])
// blocks [2304,2592): WO[((k*8+c/32)*32 +o)*32 + c%32] = bf16(w_off[o][c][k]) (o<27, else 0)
__global__ __launch_bounds__(256) void prep_w_kernel(
    const float* __restrict__ w_conv, const float* __restrict__ w_off,
    const float* __restrict__ b_conv,
    const float* __restrict__ gamma, const float* __restrict__ beta,
    const float* __restrict__ rmean, const float* __restrict__ rvar,
    float* __restrict__ AB, unsigned short* __restrict__ WQ,
    unsigned short* __restrict__ WO)
{
    if (blockIdx.x == 0) {
        int o = threadIdx.x;
        float sc = gamma[o] * rsqrtf(rvar[o] + EPS_);
        AB[o] = sc;
        AB[256 + o] = beta[o] + (b_conv[o] - rmean[o]) * sc;
    }
    if (blockIdx.x < 2304) {
        int idx = blockIdx.x * 256 + threadIdx.x;   // 589824 total
        int ch = idx >> 13;          // chunk = k*8 + c/32
        int o  = (idx >> 5) & 255;
        int cp = idx & 31;
        int c  = ((ch & 7) << 5) + cp;
        int k  = ch >> 3;
        WQ[idx] = f2b(w_conv[(o * C_ + c) * 9 + k]);
    } else {
        int j = (blockIdx.x - 2304) * 256 + threadIdx.x;  // 73728 total
        int ch = j >> 10;
        int o  = (j >> 5) & 31;
        int cp = j & 31;
        int c  = ((ch & 7) << 5) + cp;
        int k  = ch >> 3;
        WO[j] = (o < KO_) ? f2b(w_off[(o * C_ + c) * 9 + k]) : (unsigned short)0;
    }
}

// ---------------- kernel 2: x NCHW f32 -> NHWC bf16 ----------------
__global__ __launch_bounds__(256) void xt_kernel(const float* __restrict__ x,
                                                 unsigned short* __restrict__ XT)
{
    __shared__ unsigned short ls[32][100];
    int h  = blockIdx.x;
    int cg = blockIdx.y & 7;
    int b  = blockIdx.y >> 3;
    int c0 = cg * 32;
    for (int e = threadIdx.x; e < 32 * W_; e += 256) {
        int ci = e / W_, w = e % W_;
        ls[ci][w] = f2b(x[((b * C_ + c0 + ci) * H_ + h) * W_ + w]);
    }
    __syncthreads();
    for (int e = threadIdx.x; e < 32 * W_; e += 256) {
        int w = e >> 5, ci = e & 31;
        XT[((b * H_ + h) * W_ + w) * C_ + c0 + ci] = ls[ci][w];
    }
}

// ---------------- kernel 3: offset conv as LDS-free MFMA GEMM ----------------
// M=32 (27 real outputs), K=2304, per-block N=64 px (wave=16 px = one tile row).
// B-fragment loaded per-lane directly from XT (coalesced); A from WO (L2-hot).
// Depth-4 register pipeline, no barriers. Epilogue: +bias, sigmoid, -> DY/DX/MK.
__global__ __launch_bounds__(256, 4) void offmfma_kernel(
    const unsigned short* __restrict__ XT,
    const unsigned short* __restrict__ WO,
    const float* __restrict__ b_off,
    float* __restrict__ DY, float* __restrict__ DX, float* __restrict__ MK)
{
    const int tid = threadIdx.x;
    const int b  = blockIdx.z;
    const int ht = blockIdx.x / 6, wt = blockIdx.x % 6;
    const int h0 = ht * 4, w0 = wt * 16;

    const int wave = tid >> 6;
    const int lane = tid & 63;
    const int quad = lane >> 4;
    const int l15  = lane & 15;

    const int ph = h0 + wave;       // this wave's pixel row
    const int pw = w0 + l15;        // this lane's pixel col (B operand n-index)

    float4v acc[2];
    acc[0] = float4v{0.f, 0.f, 0.f, 0.f};
    acc[1] = float4v{0.f, 0.f, 0.f, 0.f};

    int basec; bool vld;
    auto compute_base = [&](int k) {
        int py  = ph + (k / 3) - 1;
        int pxl = pw + (k % 3) - 1;
        vld = ((unsigned)py < (unsigned)H_) && ((unsigned)pxl < (unsigned)W_);
        int pyc = min(max(py, 0), H_ - 1);
        int pxc = min(max(pxl, 0), W_ - 1);
        basec = ((b * H_ + pyc) * W_ + pxc) * C_ + quad * 8;
    };
    auto g_load = [&](int ch) -> ushort8 {
        ushort8 v = *(const ushort8*)(XT + basec + (ch & 7) * 32);
#pragma unroll
        for (int j = 0; j < 8; j++) v[j] = vld ? v[j] : (unsigned short)0;
        return v;
    };

    ushort8 bq0, bq1, bq2, bq3;
    short8v aq[4][2];
    auto load_w = [&](int ch, short8v A[2]) {
        const unsigned short* p = WO + ch * 1024 + l15 * 32 + quad * 8;
        A[0] = *(const short8v*)(p);
        A[1] = *(const short8v*)(p + 512);
    };

    // prologue: chunks 0..3 (all k=0)
    compute_base(0);
    bq0 = g_load(0); bq1 = g_load(1); bq2 = g_load(2); bq3 = g_load(3);
    load_w(0, aq[0]); load_w(1, aq[1]); load_w(2, aq[2]); load_w(3, aq[3]);

    auto step = [&](int ch, ushort8& slot, short8v A[2]) {
        int p = ch + 4;
        if (p < NCH_ && (p & 7) == 0) compute_base(p >> 3);
        ushort8 bv = slot;
        short8v a0 = A[0], a1 = A[1];
        if (p < NCH_) { slot = g_load(p); load_w(p, A); }
        union { ushort8 u; short8v s; } cb; cb.u = bv;
        acc[0] = __builtin_amdgcn_mfma_f32_16x16x32_bf16(a0, cb.s, acc[0], 0, 0, 0);
        acc[1] = __builtin_amdgcn_mfma_f32_16x16x32_bf16(a1, cb.s, acc[1], 0, 0, 0);
    };

    for (int it = 0; it < NCH_; it += 4) {
        step(it,     bq0, aq[0]);
        step(it + 1, bq1, aq[1]);
        step(it + 2, bq2, aq[2]);
        step(it + 3, bq3, aq[3]);
    }

    // epilogue: o = mt*16 + quad*4 + r ; pixel = (ph, pw)
    const int pix = ph * W_ + pw;
#pragma unroll
    for (int mt = 0; mt < 2; mt++) {
#pragma unroll
        for (int r = 0; r < 4; r++) {
            int o = mt * 16 + quad * 4 + r;
            if (o >= KO_) continue;
            float v = acc[mt][r] + b_off[o];
            if (o < 18) {
                int k = o >> 1;
                float* dst = (o & 1) ? DX : DY;
                dst[(b * 9 + k) * HW_ + pix] = v;
            } else {
                MK[(b * 9 + (o - 18)) * HW_ + pix] = 1.f / (1.f + expf(-v));
            }
        }
    }
}

// ---------------- kernel 4: deformable GEMM (bf16 MFMA), depth-2 pipeline ----
__global__ __launch_bounds__(256, 2) void deform_kernel(
    const float* __restrict__ x, const unsigned short* __restrict__ XT,
    const unsigned short* __restrict__ WQ,
    const float* __restrict__ DY, const float* __restrict__ DX,
    const float* __restrict__ MK, const float* __restrict__ AB,
    float* __restrict__ out)
{
    __shared__ __align__(16) unsigned short s_s[2][64][72];

    const int tid = threadIdx.x;
    const int b  = blockIdx.z;
    const int o0 = blockIdx.y * 128;
    const int ht = blockIdx.x / 6, wt = blockIdx.x % 6;
    const int h0 = ht * 4, w0 = wt * 16;

    const int sub  = tid & 3;
    const int pp_f = tid >> 2;
    const int ph_f = h0 + (pp_f >> 4);
    const int pw_f = w0 + (pp_f & 15);
    const int pix_f = ph_f * W_ + pw_f;

    const int wave = tid >> 6;
    const int lane = tid & 63;
    const int quad = lane >> 4;
    const int l15  = lane & 15;
    const int wo = (wave >> 1) * 64;
    const int wp = (wave & 1) * 32;

    const unsigned short* wbase = WQ + (o0 + wo + l15) * 32 + quad * 8;

    float4v acc[4][2];
#pragma unroll
    for (int i = 0; i < 4; i++)
#pragma unroll
        for (int j = 0; j < 2; j++)
            acc[i][j] = float4v{0.f, 0.f, 0.f, 0.f};

    const float* DYb = DY + b * 9 * HW_ + pix_f;
    const float* DXb = DX + b * 9 * HW_ + pix_f;
    const float* MKb = MK + b * 9 * HW_ + pix_f;

    int a00, a01, a10, a11;
    float fwc0, fwc1, fwc2, fwc3;
    float fwn0, fwn1, fwn2, fwn3;
    float nk_dy = 0.f, nk_dx = 0.f, nk_m = 0.f;

    auto make_params = [&](int k, float dyv, float dxv, float m) {
        float py = (float)(ph_f + (k / 3) - 1) + dyv;
        float pxx = (float)(pw_f + (k % 3) - 1) + dxv;
        float y0f = floorf(py), x0f = floorf(pxx);
        float ly = py - y0f, lx = pxx - x0f;
        int y0 = (int)y0f, x0i = (int)x0f;
        int y1 = y0 + 1, x1 = x0i + 1;
        bool vy0 = (unsigned)y0 < (unsigned)H_;
        bool vy1 = (unsigned)y1 < (unsigned)H_;
        bool vx0 = (unsigned)x0i < (unsigned)W_;
        bool vx1 = (unsigned)x1 < (unsigned)W_;
        fwn0 = (vy0 && vx0) ? (1.f - ly) * (1.f - lx) * m : 0.f;
        fwn1 = (vy0 && vx1) ? (1.f - ly) * lx * m : 0.f;
        fwn2 = (vy1 && vx0) ? ly * (1.f - lx) * m : 0.f;
        fwn3 = (vy1 && vx1) ? ly * lx * m : 0.f;
        int y0c = min(max(y0, 0), H_ - 1), y1c = min(max(y1, 0), H_ - 1);
        int x0c = min(max(x0i, 0), W_ - 1), x1c = min(max(x1, 0), W_ - 1);
        a00 = ((b * H_ + y0c) * W_ + x0c) * C_ + sub * 8;
        a01 = ((b * H_ + y0c) * W_ + x1c) * C_ + sub * 8;
        a10 = ((b * H_ + y1c) * W_ + x0c) * C_ + sub * 8;
        a11 = ((b * H_ + y1c) * W_ + x1c) * C_ + sub * 8;
    };

    struct GS { ushort8 v00, v01, v10, v11; };
    short8v a_cur[4], a_nxt[4];
    GS g0, g1;

    auto load_g = [&](int ch, GS& g) {
        const int co = (ch & 7) * 32;
        g.v00 = *(const ushort8*)(XT + a00 + co);
        g.v01 = *(const ushort8*)(XT + a01 + co);
        g.v10 = *(const ushort8*)(XT + a10 + co);
        g.v11 = *(const ushort8*)(XT + a11 + co);
    };
    auto load_w = [&](int ch, short8v A[4]) {
        const unsigned short* p = wbase + ch * 8192;
#pragma unroll
        for (int mt = 0; mt < 4; ++mt)
            A[mt] = *(const short8v*)(p + mt * 512);
    };
    auto lerp_store = [&](const GS& g, unsigned short (*sw)[72]) {
        float v[8];
#pragma unroll
        for (int j = 0; j < 8; j++)
            v[j] = fwc0 * b2f(g.v00[j]) + fwc1 * b2f(g.v01[j])
                 + fwc2 * b2f(g.v10[j]) + fwc3 * b2f(g.v11[j]);
        uint4 sv;
        sv.x = pack2(v[0], v[1]);
        sv.y = pack2(v[2], v[3]);
        sv.z = pack2(v[4], v[5]);
        sv.w = pack2(v[6], v[7]);
        *(uint4*)&sw[pp_f][sub * 8] = sv;
    };

    {
        float d0 = DYb[0], e0 = DXb[0], m0 = MKb[0];
        nk_dy = DYb[HW_]; nk_dx = DXb[HW_]; nk_m = MKb[HW_];
        make_params(0, d0, e0, m0);
        fwc0 = fwn0; fwc1 = fwn1; fwc2 = fwn2; fwc3 = fwn3;
    }
    load_g(0, g0);
    load_g(1, g1);
    load_w(0, a_cur);
    lerp_store(g0, s_s[0]);
    __syncthreads();

    auto step = [&](int ch, unsigned short (*sr)[72], unsigned short (*sw)[72],
                    GS& gld, GS& gst) {
        const int c2 = ch + 2;
        if (c2 < NCH_ && (c2 & 7) == 0) {
            const int k2 = c2 >> 3;
            make_params(k2, nk_dy, nk_dx, nk_m);
            if (k2 < 8) {
                nk_dy = DYb[(k2 + 1) * HW_];
                nk_dx = DXb[(k2 + 1) * HW_];
                nk_m  = MKb[(k2 + 1) * HW_];
            }
        }
        if (c2 < NCH_) load_g(c2, gld);
        if (ch + 1 < NCH_) load_w(ch + 1, a_nxt);
        short8v b0 = *(const short8v*)&sr[wp + l15][quad * 8];
        short8v b1 = *(const short8v*)&sr[wp + 16 + l15][quad * 8];
#pragma unroll
        for (int mt = 0; mt < 4; ++mt) {
            acc[mt][0] = __builtin_amdgcn_mfma_f32_16x16x32_bf16(
                a_cur[mt], b0, acc[mt][0], 0, 0, 0);
            acc[mt][1] = __builtin_amdgcn_mfma_f32_16x16x32_bf16(
                a_cur[mt], b1, acc[mt][1], 0, 0, 0);
        }
        if (ch + 1 < NCH_) lerp_store(gst, sw);
        fwc0 = fwn0; fwc1 = fwn1; fwc2 = fwn2; fwc3 = fwn3;
#pragma unroll
        for (int mt = 0; mt < 4; ++mt) a_cur[mt] = a_nxt[mt];
        if (ch + 1 < NCH_) __syncthreads();
    };

    for (int it = 0; it < NCH_; it += 2) {
        step(it,     s_s[0], s_s[1], g0, g1);
        step(it + 1, s_s[1], s_s[0], g1, g0);
    }

    const float* Ao = AB;
    const float* Bo = AB + 256;
#pragma unroll
    for (int mt = 0; mt < 4; mt++) {
#pragma unroll
        for (int nt = 0; nt < 2; nt++) {
            int p = wp + nt * 16 + l15;
            int ph = h0 + (p >> 4), pw = w0 + (p & 15);
#pragma unroll
            for (int r = 0; r < 4; r++) {
                int o = o0 + wo + mt * 16 + quad * 4 + r;
                float v = acc[mt][nt][r] * Ao[o] + Bo[o];
                v = fmaxf(v, 0.f);
                int gi = ((b * C_ + o) * H_ + ph) * W_ + pw;
                out[gi] = x[gi] + v;
            }
        }
    }
}

extern "C" void kernel_launch(void* const* d_in, const int* in_sizes, int n_in,
                              void* d_out, int out_size, void* d_ws, size_t ws_size,
                              hipStream_t stream)
{
    (void)in_sizes; (void)n_in; (void)out_size; (void)ws_size;
    const float* x      = (const float*)d_in[0];
    const float* w_off  = (const float*)d_in[1];
    const float* b_off  = (const float*)d_in[2];
    const float* w_conv = (const float*)d_in[3];
    const float* b_conv = (const float*)d_in[4];
    const float* gamma  = (const float*)d_in[5];
    const float* beta   = (const float*)d_in[6];
    const float* rmean  = (const float*)d_in[7];
    const float* rvar   = (const float*)d_in[8];
    float* out = (float*)d_out;

    float* ws = (float*)d_ws;
    float* DY = ws;                            // 2*9*9216
    float* DX = DY + 2 * 9 * HW_;
    float* MK = DX + 2 * 9 * HW_;
    float* AB = MK + 2 * 9 * HW_;              // 512
    unsigned short* WQ = (unsigned short*)(AB + 512);   // 589824 bf16
    unsigned short* WO = WQ + 589824;                   // 73728 bf16
    unsigned short* XT = WO + 73728;                    // 2*9216*256 bf16

    prep_w_kernel<<<2592, 256, 0, stream>>>(w_conv, w_off, b_conv, gamma, beta,
                                            rmean, rvar, AB, WQ, WO);
    xt_kernel<<<dim3(96, 16), 256, 0, stream>>>(x, XT);
    offmfma_kernel<<<dim3(144, 1, 2), 256, 0, stream>>>(XT, WO, b_off, DY, DX, MK);
    deform_kernel<<<dim3(144, 2, 2), 256, 0, stream>>>(x, XT, WQ, DY, DX, MK, AB, out);
}